// Round 1
// baseline (148.445 us; speedup 1.0000x reference)
//
#include <hip/hip_runtime.h>
#include <hip/hip_bf16.h>

#define NN 8192
#define DD 128
#define BM 16
#define BK 64
#define NT (NN / BK)

typedef __attribute__((ext_vector_type(4))) float f32x4;
typedef __attribute__((ext_vector_type(8))) short bf16x8;
typedef __attribute__((ext_vector_type(4))) unsigned short u16x4;

__device__ __forceinline__ unsigned short f2bf(float x) {
    unsigned u = __float_as_uint(x);
    u += 0x7fffu + ((u >> 16) & 1u);   // round-to-nearest-even
    return (unsigned short)(u >> 16);
}

typedef const __attribute__((address_space(1))) unsigned int* gas_ptr;
typedef __attribute__((address_space(3))) unsigned int* las_ptr;

__device__ __forceinline__ void gload_lds16(const void* g, void* l) {
    __builtin_amdgcn_global_load_lds((gas_ptr)g, (las_ptr)l, 16, 0, 0);
}

// ---------------------------------------------------------------------------
// Kernel A: hT[n][j] = bf16( B[n] + sum_k z[j][k] * W[k][n] ),
// stored PRE-SWIZZLED within each 64-element (128 B) chunk:
//   hT_ws[n*8192 + kt*64 + (kc ^ ((n&7)<<3))] = h[kt*64+kc][n]
// so kernel B's linear global_load_lds lands the XOR-swizzled LDS layout.
// ---------------------------------------------------------------------------
__global__ void __launch_bounds__(256) h_transform(
    const float* __restrict__ z, const float* __restrict__ W,
    const float* __restrict__ Bv, unsigned short* __restrict__ hT) {
    __shared__ float zs[BM * DD];      // 16 x 128 f32 (8 KB)
    __shared__ float wt[DD * 132];     // W transposed [n][k], pad 132 (67.6 KB)
    const int t = threadIdx.x;
    const int j0 = blockIdx.x * BM;

    {   // stage z rows
        const f32x4* zsrc = (const f32x4*)(z + (size_t)j0 * DD);
        f32x4* zdst = (f32x4*)zs;
        zdst[t] = zsrc[t];
        zdst[t + 256] = zsrc[t + 256];
    }
    // stage W transposed
    for (int q = t; q < DD * 32; q += 256) {
        int k = q >> 5;
        int n0 = (q & 31) << 2;
        f32x4 wv = *(const f32x4*)(W + k * DD + n0);
        wt[(n0 + 0) * 132 + k] = wv[0];
        wt[(n0 + 1) * 132 + k] = wv[1];
        wt[(n0 + 2) * 132 + k] = wv[2];
        wt[(n0 + 3) * 132 + k] = wv[3];
    }
    __syncthreads();

    const int n = t >> 1;          // 0..127
    const int ja = (t & 1) << 3;   // 0 or 8
    float acc[8];
    float bn = Bv[n];
#pragma unroll
    for (int e = 0; e < 8; e++) acc[e] = bn;

#pragma unroll 8
    for (int k4 = 0; k4 < 32; ++k4) {
        f32x4 wv = *(const f32x4*)&wt[n * 132 + (k4 << 2)];
#pragma unroll
        for (int e = 0; e < 8; e++) {
            f32x4 zv = *(const f32x4*)&zs[(ja + e) * DD + (k4 << 2)];
            acc[e] += zv[0] * wv[0] + zv[1] * wv[1] + zv[2] * wv[2] + zv[3] * wv[3];
        }
    }

    const int j = j0 + ja;                 // 8-aligned
    const int kt = j >> 6;
    const int kc = j & 63;
    const int kcs = kc ^ ((n & 7) << 3);   // pre-swizzle (element units)
    unsigned short* dst = hT + (size_t)n * NN + kt * 64 + kcs;
    uint4 uv;
    uv.x = (unsigned)f2bf(acc[0]) | ((unsigned)f2bf(acc[1]) << 16);
    uv.y = (unsigned)f2bf(acc[2]) | ((unsigned)f2bf(acc[3]) << 16);
    uv.z = (unsigned)f2bf(acc[4]) | ((unsigned)f2bf(acc[5]) << 16);
    uv.w = (unsigned)f2bf(acc[6]) | ((unsigned)f2bf(acc[7]) << 16);
    *(uint4*)dst = uv;
}

// ---------------------------------------------------------------------------
// Kernel B: fused S-compute + S@h GEMM.
// Block: 16 output rows x 128 cols, K-loop over 8192 in steps of 64.
// 4 waves; wave w owns output cols [32w, 32w+32) via 2 accumulators.
// Double-buffered LDS; h tile via global_load_lds (linear dest, pre-swizzled
// source); S tile computed in regs and ds_written with the same XOR swizzle.
// ---------------------------------------------------------------------------
__global__ void __launch_bounds__(256) fused_interact(
    const float* __restrict__ dist, const unsigned short* __restrict__ hT,
    const float* __restrict__ mu, const float* __restrict__ sigma,
    float* __restrict__ out) {
    __shared__ unsigned short sS[2][BM * BK];   // 2 x 2 KB, swizzled [row][k]
    __shared__ unsigned short sH[2][DD * BK];   // 2 x 16 KB, swizzled [n][k]

    const int t = threadIdx.x;
    const int w = t >> 6;
    const int l = t & 63;
    const int i0 = blockIdx.x * BM;

    const float inv_mu = 1.0f / mu[0];
    const float sg = sigma[0];
    const float inv2s2 = 1.0f / (2.0f * sg * sg);

    // S staging: thread -> (row sr, 4 cols at sc)
    const int sr = t >> 4;
    const int sc = (t & 15) << 2;
    const float* drow = dist + (size_t)(i0 + sr) * NN + sc;
    const int diag = i0 + sr;
    const int swb = (sr * 128 + (sc << 1)) ^ ((sr & 7) << 4);  // byte offset

    // MFMA fragment read offsets (bytes, swizzled)
    const int arow = l & 15;
    const int aq = (l >> 4) << 4;          // 0,16,32,48
    const int aswz = (arow & 7) << 4;
    const int a_off0 = arow * 128 + (aq ^ aswz);
    const int a_off1 = arow * 128 + ((64 + aq) ^ aswz);

    const int bn0 = (w << 5) + (l & 15);
    const int bn1 = bn0 + 16;
    const int b00o = bn0 * 128 + (aq ^ ((bn0 & 7) << 4));
    const int b01o = bn0 * 128 + ((64 + aq) ^ ((bn0 & 7) << 4));
    const int b10o = bn1 * 128 + (aq ^ ((bn1 & 7) << 4));
    const int b11o = bn1 * 128 + ((64 + aq) ^ ((bn1 & 7) << 4));

    f32x4 acc0 = {0.f, 0.f, 0.f, 0.f};
    f32x4 acc1 = {0.f, 0.f, 0.f, 0.f};

    // prologue: stage tile 0 into buffer 0
    {
#pragma unroll
        for (int p = 0; p < 4; p++) {
            int q = p * 256 + t;
            const unsigned short* g = hT + (size_t)(q >> 3) * NN + ((q & 7) << 3);
            gload_lds16(g, (void*)&sH[0][(p * 256 + (w << 6)) << 3]);
        }
        f32x4 dv = *(const f32x4*)(drow);
        u16x4 sv;
#pragma unroll
        for (int e = 0; e < 4; e++) {
            float d = dv[e];
            int jj = sc + e;
            float q = __builtin_amdgcn_rcpf(d) - inv_mu;
            float s = __expf(-(q * q) * inv2s2);
            sv[e] = f2bf(((d < 0.5f) && (jj != diag)) ? s : 0.0f);
        }
        *(u16x4*)((char*)&sS[0][0] + swb) = sv;
    }
    __syncthreads();

    int cur = 0;
    for (int kt = 0; kt < NT; ++kt) {
        const int nxt = cur ^ 1;
        const int kb2 = (kt + 1) << 6;
        f32x4 dv;
        if (kt < NT - 1) {
            // issue next h tile (direct-to-LDS) and next dist loads first
#pragma unroll
            for (int p = 0; p < 4; p++) {
                int q = p * 256 + t;
                const unsigned short* g =
                    hT + (size_t)(q >> 3) * NN + kb2 + ((q & 7) << 3);
                gload_lds16(g, (void*)&sH[nxt][(p * 256 + (w << 6)) << 3]);
            }
            dv = *(const f32x4*)(drow + kb2);
        }
        // MFMA on current buffers
        {
            const char* Sb = (const char*)&sS[cur][0];
            const char* Hb = (const char*)&sH[cur][0];
            bf16x8 a0 = *(const bf16x8*)(Sb + a_off0);
            bf16x8 a1 = *(const bf16x8*)(Sb + a_off1);
            bf16x8 b00 = *(const bf16x8*)(Hb + b00o);
            bf16x8 b10 = *(const bf16x8*)(Hb + b10o);
            bf16x8 b01 = *(const bf16x8*)(Hb + b01o);
            bf16x8 b11 = *(const bf16x8*)(Hb + b11o);
            acc0 = __builtin_amdgcn_mfma_f32_16x16x32_bf16(a0, b00, acc0, 0, 0, 0);
            acc1 = __builtin_amdgcn_mfma_f32_16x16x32_bf16(a0, b10, acc1, 0, 0, 0);
            acc0 = __builtin_amdgcn_mfma_f32_16x16x32_bf16(a1, b01, acc0, 0, 0, 0);
            acc1 = __builtin_amdgcn_mfma_f32_16x16x32_bf16(a1, b11, acc1, 0, 0, 0);
        }
        if (kt < NT - 1) {
            // compute next S tile while MFMA results drain
            u16x4 sv;
#pragma unroll
            for (int e = 0; e < 4; e++) {
                float d = dv[e];
                int jj = kb2 + sc + e;
                float q = __builtin_amdgcn_rcpf(d) - inv_mu;
                float s = __expf(-(q * q) * inv2s2);
                sv[e] = f2bf(((d < 0.5f) && (jj != diag)) ? s : 0.0f);
            }
            *(u16x4*)((char*)&sS[nxt][0] + swb) = sv;
        }
        __syncthreads();
        cur = nxt;
    }

    // epilogue: C fragment layout col = lane&15, row = (lane>>4)*4 + reg
    const int orow = i0 + ((l >> 4) << 2);
    const int ocol = (w << 5) + (l & 15);
#pragma unroll
    for (int rr = 0; rr < 4; ++rr) {
        out[(size_t)(orow + rr) * DD + ocol] = acc0[rr];
        out[(size_t)(orow + rr) * DD + ocol + 16] = acc1[rr];
    }
}

extern "C" void kernel_launch(void* const* d_in, const int* in_sizes, int n_in,
                              void* d_out, int out_size, void* d_ws, size_t ws_size,
                              hipStream_t stream) {
    const float* z = (const float*)d_in[0];
    const float* dist = (const float*)d_in[1];
    const float* W = (const float*)d_in[2];
    const float* Bv = (const float*)d_in[3];
    const float* mu = (const float*)d_in[4];
    const float* sigma = (const float*)d_in[5];
    float* out = (float*)d_out;
    unsigned short* hT = (unsigned short*)d_ws;  // 128*8192 bf16 = 2 MB

    h_transform<<<NN / BM, 256, 0, stream>>>(z, W, Bv, hT);
    fused_interact<<<NN / BM, 256, 0, stream>>>(dist, hT, mu, sigma, out);
}

// Round 2
// 132.641 us; speedup vs baseline: 1.1192x; 1.1192x over previous
//
#include <hip/hip_runtime.h>
#include <hip/hip_bf16.h>

#define NN 8192
#define DD 128
#define BM 16

typedef __attribute__((ext_vector_type(4))) float f32x4;
typedef __attribute__((ext_vector_type(8))) short bf16x8;

__device__ __forceinline__ unsigned short f2bf(float x) {
    unsigned u = __float_as_uint(x);
    u += 0x7fffu + ((u >> 16) & 1u);   // round-to-nearest-even
    return (unsigned short)(u >> 16);
}

// ---------------------------------------------------------------------------
// Kernel A: hT[n][j] = bf16( B[n] + sum_k z[j][k] * W[k][n] ), plain layout.
// ---------------------------------------------------------------------------
__global__ void __launch_bounds__(256) h_transform(
    const float* __restrict__ z, const float* __restrict__ W,
    const float* __restrict__ Bv, unsigned short* __restrict__ hT) {
    __shared__ float zs[BM * DD];      // 16 x 128 f32 (8 KB)
    __shared__ float wt[DD * 132];     // W transposed [n][k], pad 132
    const int t = threadIdx.x;
    const int j0 = blockIdx.x * BM;

    {   // stage z rows
        const f32x4* zsrc = (const f32x4*)(z + (size_t)j0 * DD);
        f32x4* zdst = (f32x4*)zs;
        zdst[t] = zsrc[t];
        zdst[t + 256] = zsrc[t + 256];
    }
    // stage W transposed
    for (int q = t; q < DD * 32; q += 256) {
        int k = q >> 5;
        int n0 = (q & 31) << 2;
        f32x4 wv = *(const f32x4*)(W + k * DD + n0);
        wt[(n0 + 0) * 132 + k] = wv[0];
        wt[(n0 + 1) * 132 + k] = wv[1];
        wt[(n0 + 2) * 132 + k] = wv[2];
        wt[(n0 + 3) * 132 + k] = wv[3];
    }
    __syncthreads();

    const int n = t >> 1;          // 0..127
    const int ja = (t & 1) << 3;   // 0 or 8
    float acc[8];
    float bn = Bv[n];
#pragma unroll
    for (int e = 0; e < 8; e++) acc[e] = bn;

#pragma unroll 8
    for (int k4 = 0; k4 < 32; ++k4) {
        f32x4 wv = *(const f32x4*)&wt[n * 132 + (k4 << 2)];
#pragma unroll
        for (int e = 0; e < 8; e++) {
            f32x4 zv = *(const f32x4*)&zs[(ja + e) * DD + (k4 << 2)];
            acc[e] += zv[0] * wv[0] + zv[1] * wv[1] + zv[2] * wv[2] + zv[3] * wv[3];
        }
    }

    const int j = j0 + ja;                 // 8-aligned
    unsigned short* dst = hT + (size_t)n * NN + j;
    uint4 uv;
    uv.x = (unsigned)f2bf(acc[0]) | ((unsigned)f2bf(acc[1]) << 16);
    uv.y = (unsigned)f2bf(acc[2]) | ((unsigned)f2bf(acc[3]) << 16);
    uv.z = (unsigned)f2bf(acc[4]) | ((unsigned)f2bf(acc[5]) << 16);
    uv.w = (unsigned)f2bf(acc[6]) | ((unsigned)f2bf(acc[7]) << 16);
    *(uint4*)dst = uv;
}

// ---------------------------------------------------------------------------
// Kernel B: fully barrier-free fused S-compute + S@h GEMM.
// One wave (64 thr) per block. Wave owns 32 output rows x 128 cols, K-range
// [kbeg, kbeg+klen). A-frag (S) loaded as dist directly in MFMA lane layout
// (row = lane&15, k = (lane>>4)*8+e), converted in-register. B-frag (hT)
// loaded register-direct from L2-resident hT. Register double-buffer,
// zero LDS, zero __syncthreads -> loads stay in flight across iterations.
// ---------------------------------------------------------------------------
__device__ __forceinline__ bf16x8 sfrag(f32x4 a, f32x4 b, int jbase, int diag,
                                        float inv_mu, float ninv2s2) {
    float v0[4] = {a[0], a[1], a[2], a[3]};
    float v1[4] = {b[0], b[1], b[2], b[3]};
    unsigned short h[8];
#pragma unroll
    for (int e = 0; e < 4; ++e) {
        float d = v0[e];
        float q = __builtin_amdgcn_rcpf(d) - inv_mu;
        float s = __expf(q * q * ninv2s2);
        bool keep = (d < 0.5f) & ((jbase + e) != diag);
        h[e] = f2bf(keep ? s : 0.0f);
    }
#pragma unroll
    for (int e = 0; e < 4; ++e) {
        float d = v1[e];
        float q = __builtin_amdgcn_rcpf(d) - inv_mu;
        float s = __expf(q * q * ninv2s2);
        bool keep = (d < 0.5f) & ((jbase + 4 + e) != diag);
        h[4 + e] = f2bf(keep ? s : 0.0f);
    }
    uint4 u;
    u.x = (unsigned)h[0] | ((unsigned)h[1] << 16);
    u.y = (unsigned)h[2] | ((unsigned)h[3] << 16);
    u.z = (unsigned)h[4] | ((unsigned)h[5] << 16);
    u.w = (unsigned)h[6] | ((unsigned)h[7] << 16);
    return __builtin_bit_cast(bf16x8, u);
}

__global__ void __launch_bounds__(64) fused_interact(
    const float* __restrict__ dist, const unsigned short* __restrict__ hT,
    const float* __restrict__ mu, const float* __restrict__ sigma,
    float* __restrict__ outp, float* __restrict__ part, int ksplit) {
    const int l = threadIdx.x;
    const int rt = blockIdx.x / ksplit;
    const int ks = blockIdx.x - rt * ksplit;
    const int klen = NN / ksplit;
    const int kbeg = ks * klen;

    const int row = l & 15;
    const int kc8 = (l >> 4) << 3;
    const int r0 = rt * 32;

    const float inv_mu = 1.0f / mu[0];
    const float sg = sigma[0];
    const float ninv2s2 = -1.0f / (2.0f * sg * sg);

    const float* dp0 = dist + (size_t)(r0 + row) * NN + kc8;
    const float* dp1 = dp0 + (size_t)16 * NN;
    const unsigned short* hp = hT + (size_t)row * NN + kc8;
    const int diag0 = r0 + row;
    const int diag1 = diag0 + 16;

    f32x4 acc[2][8];
#pragma unroll
    for (int m = 0; m < 2; ++m)
#pragma unroll
        for (int f = 0; f < 8; ++f) acc[m][f] = (f32x4){0.f, 0.f, 0.f, 0.f};

    f32x4 dA0a, dA0b, dA1a, dA1b, dB0a, dB0b, dB1a, dB1b;
    uint4 hA[8], hB[8];

#define LOADD(Da, Db, Dc, Dd, H, K)                                          \
    do {                                                                     \
        Da = *(const f32x4*)(dp0 + (K));                                     \
        Db = *(const f32x4*)(dp0 + (K) + 4);                                 \
        Dc = *(const f32x4*)(dp1 + (K));                                     \
        Dd = *(const f32x4*)(dp1 + (K) + 4);                                 \
        _Pragma("unroll") for (int f = 0; f < 8; ++f)                        \
            H[f] = *(const uint4*)(hp + (size_t)f * 16 * NN + (K));          \
    } while (0)

#define COMPUTE(Da, Db, Dc, Dd, H, K)                                        \
    do {                                                                     \
        bf16x8 a0 = sfrag(Da, Db, (K) + kc8, diag0, inv_mu, ninv2s2);        \
        bf16x8 a1 = sfrag(Dc, Dd, (K) + kc8, diag1, inv_mu, ninv2s2);        \
        _Pragma("unroll") for (int f = 0; f < 8; ++f) {                      \
            bf16x8 bb = __builtin_bit_cast(bf16x8, H[f]);                    \
            acc[0][f] = __builtin_amdgcn_mfma_f32_16x16x32_bf16(             \
                a0, bb, acc[0][f], 0, 0, 0);                                 \
            acc[1][f] = __builtin_amdgcn_mfma_f32_16x16x32_bf16(             \
                a1, bb, acc[1][f], 0, 0, 0);                                 \
        }                                                                    \
    } while (0)

    int k = kbeg;
    LOADD(dA0a, dA0b, dA1a, dA1b, hA, k);
    LOADD(dB0a, dB0b, dB1a, dB1b, hB, k + 32);
    const int nt = klen >> 5;   // iterations of K=32; always even here
    for (int it = 0; it < nt; it += 2) {
        COMPUTE(dA0a, dA0b, dA1a, dA1b, hA, k);
        if (it + 2 < nt) LOADD(dA0a, dA0b, dA1a, dA1b, hA, k + 64);
        COMPUTE(dB0a, dB0b, dB1a, dB1b, hB, k + 32);
        if (it + 3 < nt) LOADD(dB0a, dB0b, dB1a, dB1b, hB, k + 96);
        k += 64;
    }

    float* po = (ksplit == 1) ? outp : (part + (size_t)ks * (NN * DD));
    const int orow = r0 + ((l >> 4) << 2);
    const int ocol = l & 15;
#pragma unroll
    for (int m = 0; m < 2; ++m)
#pragma unroll
        for (int f = 0; f < 8; ++f)
#pragma unroll
            for (int rr = 0; rr < 4; ++rr)
                po[(size_t)(orow + m * 16 + rr) * DD + f * 16 + ocol] =
                    acc[m][f][rr];
}

// ---------------------------------------------------------------------------
// Kernel C: sum K-split partials into out.
// ---------------------------------------------------------------------------
__global__ void __launch_bounds__(256) reduce_part(
    const float* __restrict__ part, float* __restrict__ outp, int ksplit) {
    const size_t idx = ((size_t)blockIdx.x * 256 + threadIdx.x) << 2;
    f32x4 s = *(const f32x4*)(part + idx);
    for (int ksp = 1; ksp < ksplit; ++ksp)
        s += *(const f32x4*)(part + (size_t)ksp * (NN * DD) + idx);
    *(f32x4*)(outp + idx) = s;
}

extern "C" void kernel_launch(void* const* d_in, const int* in_sizes, int n_in,
                              void* d_out, int out_size, void* d_ws, size_t ws_size,
                              hipStream_t stream) {
    const float* z = (const float*)d_in[0];
    const float* dist = (const float*)d_in[1];
    const float* W = (const float*)d_in[2];
    const float* Bv = (const float*)d_in[3];
    const float* mu = (const float*)d_in[4];
    const float* sigma = (const float*)d_in[5];
    float* out = (float*)d_out;

    unsigned short* hT = (unsigned short*)d_ws;           // 2 MB
    const size_t hT_bytes = (size_t)DD * NN * 2;
    const size_t part_bytes = (size_t)NN * DD * 4;        // 4 MB per split
    float* part = (float*)((char*)d_ws + hT_bytes);

    int ksplit = 1;
    if (ws_size >= hT_bytes + 4 * part_bytes) ksplit = 4;
    else if (ws_size >= hT_bytes + 2 * part_bytes) ksplit = 2;

    h_transform<<<NN / BM, 256, 0, stream>>>(z, W, Bv, hT);
    fused_interact<<<(NN / 32) * ksplit, 64, 0, stream>>>(dist, hT, mu, sigma,
                                                          out, part, ksplit);
    if (ksplit > 1)
        reduce_part<<<(NN * DD) / 1024, 256, 0, stream>>>(part, out, ksplit);
}